// Round 3
// baseline (694.889 us; speedup 1.0000x reference)
//
#include <hip/hip_runtime.h>

// Bidirectional LSTM, B=256, T=1024, V=6, D=64, U=64; output = last-step
// concat(h_f, h_b) @ Wd + bd, shape (B,1).
// Reductions: backward dir needs exactly ONE step from h0=0 (Wr_b dead);
// V=6 -> xproj is a 6x256 table per block.
// R2: gate-interleaved lanes + shfl gather + double-buffered h -> 1 barrier/step.
// R3: __launch_bounds__(256,1). Grid is 256 blocks = 1 block/CU, so each wave
//     may use up to 512 VGPRs. Without this the compiler capped at 64 VGPRs
//     and SPILLED wr[64] to scratch, re-loading it every step (R2: VGPR=64,
//     662us). wr[64]+h4[16] must be register-resident.

constexpr int kB = 256;
constexpr int kT = 1024;
constexpr int kV = 6;
constexpr int kD = 64;
constexpr int kU = 64;
constexpr int kG = 256; // 4*U gate columns

__device__ __forceinline__ float sigmoid_f(float z) {
    return 1.0f / (1.0f + __expf(-z));   // saturates correctly at +-inf
}
__device__ __forceinline__ float tanh_fast(float x) {
    // 2*sigma(2x)-1; exp overflow/underflow saturate to +-1 correctly
    return 2.0f / (1.0f + __expf(-2.0f * x)) - 1.0f;
}

__global__ __launch_bounds__(256, 1) void bilstm_last_kernel(
    const int*   __restrict__ tokens, // (B,T)
    const float* __restrict__ emb,    // (6,64)
    const float* __restrict__ Wk_f,   // (64,256)
    const float* __restrict__ Wr_f,   // (64,256)
    const float* __restrict__ b_f,    // (256)
    const float* __restrict__ Wk_b,   // (64,256)
    const float* __restrict__ b_b,    // (256)
    const float* __restrict__ Wd,     // (128)
    const float* __restrict__ bd,     // (1)
    float*       __restrict__ out)    // (B)
{
    __shared__ float s_emb[kV * kD];
    __shared__ float s_projP[kV * kG];            // PERMUTED xproj_f table
    __shared__ int   s_tok[kT];
    __shared__ float __align__(16) s_h[2][kU];    // double-buffered hidden
    __shared__ float s_act[kG];                   // backward-step scratch
    __shared__ float s_hb[kU];
    __shared__ int   s_maskv[kV];

    const int b   = blockIdx.x;
    const int tid = threadIdx.x;
    const int l   = tid & 63;       // lane in wave
    const int wv  = tid >> 6;       // wave id 0..3
    const int g   = l & 3;          // gate 0..3 (i,f,g,o)
    const int k   = l >> 2;         // 0..15
    const int u   = wv * 16 + k;    // unit 0..63 owned by this lane group
    const int col = g * 64 + u;     // gate column this lane computes

    // ---- stage emb + tokens ----
    for (int i = tid; i < kV * kD; i += 256) s_emb[i] = emb[i];
    ((int4*)s_tok)[tid] = ((const int4*)(tokens + b * kT))[tid];
    if (tid < kU) { s_h[0][tid] = 0.0f; s_h[1][tid] = 0.0f; }
    __syncthreads();

    if (tid < kV) {
        int any = 0;
        for (int d = 0; d < kD; ++d) any |= (s_emb[tid * kD + d] != 0.0f) ? 1 : 0;
        s_maskv[tid] = any;
    }

    const int tokL = s_tok[kT - 1];

    // ---- proj table: column 'tid' (coalesced global reads), then permuted
    // store so the step loop reads s_projP[v*256 + tid] = proj[v][col(tid)].
    float accf[kV];
#pragma unroll
    for (int v = 0; v < kV; ++v) accf[v] = b_f[tid];
    float accb = b_b[tid];
    for (int d = 0; d < kD; ++d) {
        const float wkf = Wk_f[d * kG + tid];
        const float wkb = Wk_b[d * kG + tid];
#pragma unroll
        for (int v = 0; v < kV; ++v)
            accf[v] = fmaf(s_emb[v * kD + d], wkf, accf[v]);
        accb = fmaf(s_emb[tokL * kD + d], wkb, accb);
    }
    {   // inverse permutation: lane q with col(q)==tid is q = w0*64 + k0*4 + g0
        const int g0 = tid >> 6, u0 = tid & 63, w0 = u0 >> 4, k0 = u0 & 15;
        const int q = w0 * 64 + k0 * 4 + g0;
#pragma unroll
        for (int v = 0; v < kV; ++v) s_projP[v * kG + q] = accf[v];
    }

    // ---- backward single step: z = xproj_b only (h0=0, c0=0 -> f dead) ----
    float ab;
    if (tid < 128)      ab = sigmoid_f(accb);
    else if (tid < 192) ab = tanh_fast(accb);
    else                ab = sigmoid_f(accb);
    s_act[tid] = ab;
    __syncthreads();   // also makes s_maskv visible
    if (tid < kU) {
        const float cb = s_act[tid] * s_act[2 * kU + tid];
        const float hb = s_act[3 * kU + tid] * tanh_fast(cb);
        s_hb[tid] = s_maskv[tokL] ? hb : 0.0f;
    }

    // ---- recurrent weights for this lane's gate column (MUST stay in VGPRs)
    float wr[kU];
#pragma unroll
    for (int j = 0; j < kU; ++j) wr[j] = Wr_f[j * kG + col];

    float c = 0.0f, hreg = 0.0f;
    __syncthreads();   // projP + s_h init + s_hb visible

    // ---- software-pipelined token path ----
    int   tok  = s_tok[0];
    float zcur = s_projP[tok * kG + tid];
    int   msk  = s_maskv[tok];

    const int base = l & ~3;

    for (int t = 0; t < kT; ++t) {
        const int rp = t & 1, wp = rp ^ 1;

        // prefetch next step's token/proj/mask (projP is constant -> legal)
        const int   tokn  = s_tok[(t + 1) & (kT - 1)];
        const float znext = s_projP[tokn * kG + tid];
        const int   mskn  = s_maskv[tokn];

        // h broadcast loads (16 x b128, same-address broadcast)
        float4 h4[16];
#pragma unroll
        for (int j = 0; j < 16; ++j) h4[j] = ((const float4*)s_h[rp])[j];

        // 64 MACs, 4 independent chains
        float z0 = zcur, z1 = 0.0f, z2 = 0.0f, z3 = 0.0f;
#pragma unroll
        for (int j = 0; j < 16; ++j) {
            z0 = fmaf(h4[j].x, wr[4 * j + 0], z0);
            z1 = fmaf(h4[j].y, wr[4 * j + 1], z1);
            z2 = fmaf(h4[j].z, wr[4 * j + 2], z2);
            z3 = fmaf(h4[j].w, wr[4 * j + 3], z3);
        }
        const float z = (z0 + z1) + (z2 + z3);

        // one exp: gate 2 uses tanh(z) = 2*sigmoid(2z)-1
        const bool  isg = (g == 2);
        const float zz  = isg ? 2.0f * z : z;
        const float s   = 1.0f / (1.0f + __expf(-zz));
        const float a   = isg ? 2.0f * s - 1.0f : s;

        // gather i,f,g,o from the 4 lanes of this unit's quad
        const float ai = __shfl(a, base + 0, 64);
        const float af = __shfl(a, base + 1, 64);
        const float ag = __shfl(a, base + 2, 64);
        const float ao = __shfl(a, base + 3, 64);

        const float cn = fmaf(af, c, ai * ag);
        const float hn = ao * tanh_fast(cn);
        if (msk) { c = cn; hreg = hn; }

        if (g == 0) s_h[wp][u] = hreg;
        __syncthreads();

        zcur = znext; msk = mskn; tok = tokn;
    }

    // final h is in s_h[0] (step 1023 writes buffer (1024)&1 == 0)
    if (tid < kU) {
        float v = s_h[0][tid] * Wd[tid] + s_hb[tid] * Wd[kU + tid];
#pragma unroll
        for (int off = 32; off > 0; off >>= 1) v += __shfl_down(v, off, 64);
        if (tid == 0) out[b] = v + bd[0];
    }
}

extern "C" void kernel_launch(void* const* d_in, const int* in_sizes, int n_in,
                              void* d_out, int out_size, void* d_ws, size_t ws_size,
                              hipStream_t stream) {
    const int*   tokens = (const int*)d_in[0];
    const float* emb    = (const float*)d_in[1];
    const float* Wk_f   = (const float*)d_in[2];
    const float* Wr_f   = (const float*)d_in[3];
    const float* b_f    = (const float*)d_in[4];
    const float* Wk_b   = (const float*)d_in[5];
    // d_in[6] = Wr_b: unused (backward runs one step from h0=0)
    const float* b_b    = (const float*)d_in[7];
    const float* Wd     = (const float*)d_in[8];
    const float* bd     = (const float*)d_in[9];
    float* out = (float*)d_out;

    bilstm_last_kernel<<<kB, 256, 0, stream>>>(
        tokens, emb, Wk_f, Wr_f, b_f, Wk_b, b_b, Wd, bd, out);
}

// Round 4
// 689.535 us; speedup vs baseline: 1.0078x; 1.0078x over previous
//
#include <hip/hip_runtime.h>

// Bidirectional LSTM, B=256, T=1024, V=6, D=64, U=64; output = last-step
// concat(h_f, h_b) @ Wd + bd, shape (B,1).
// Reductions: backward dir needs exactly ONE step from h0=0 (Wr_b dead);
// V=6 -> xproj is a 6x256 table per block.
// R2: gate-interleaved lanes + shfl gather + double-buffered h -> 1 barrier/step.
// R4: wr[64]/h4[16] allocas were NEVER promoted to registers (SROA runs
//     before unroll; promote-alloca balks at 64-elem dyn-indexed array) ->
//     they lived in SCRATCH, ~64 buffer_loads/step/lane (R1 VGPR=44,
//     R2/R3 VGPR=64, flat 662us). Fix: macro-expanded NAMED float4 regs.

constexpr int kB = 256;
constexpr int kT = 1024;
constexpr int kV = 6;
constexpr int kD = 64;
constexpr int kU = 64;
constexpr int kG = 256; // 4*U gate columns

__device__ __forceinline__ float sigmoid_f(float z) {
    return 1.0f / (1.0f + __expf(-z));   // saturates correctly at +-inf
}
__device__ __forceinline__ float tanh_fast(float x) {
    // 2*sigma(2x)-1; exp overflow/underflow saturate to +-1 correctly
    return 2.0f / (1.0f + __expf(-2.0f * x)) - 1.0f;
}

__global__ __launch_bounds__(256, 1) void bilstm_last_kernel(
    const int*   __restrict__ tokens, // (B,T)
    const float* __restrict__ emb,    // (6,64)
    const float* __restrict__ Wk_f,   // (64,256)
    const float* __restrict__ Wr_f,   // (64,256)
    const float* __restrict__ b_f,    // (256)
    const float* __restrict__ Wk_b,   // (64,256)
    const float* __restrict__ b_b,    // (256)
    const float* __restrict__ Wd,     // (128)
    const float* __restrict__ bd,     // (1)
    float*       __restrict__ out)    // (B)
{
    __shared__ float s_emb[kV * kD];
    __shared__ float s_projP[kV * kG];            // PERMUTED xproj_f table
    __shared__ int   s_tok[kT];
    __shared__ float __align__(16) s_h[2][kU];    // double-buffered hidden
    __shared__ float s_act[kG];                   // backward-step scratch
    __shared__ float s_hb[kU];
    __shared__ int   s_maskv[kV];

    const int b   = blockIdx.x;
    const int tid = threadIdx.x;
    const int l   = tid & 63;       // lane in wave
    const int wv  = tid >> 6;       // wave id 0..3
    const int g   = l & 3;          // gate 0..3 (i,f,g,o)
    const int k   = l >> 2;         // 0..15
    const int u   = wv * 16 + k;    // unit 0..63 owned by this lane group
    const int col = g * 64 + u;     // gate column this lane computes

    // ---- stage emb + tokens ----
    for (int i = tid; i < kV * kD; i += 256) s_emb[i] = emb[i];
    ((int4*)s_tok)[tid] = ((const int4*)(tokens + b * kT))[tid];
    if (tid < kU) { s_h[0][tid] = 0.0f; s_h[1][tid] = 0.0f; }
    __syncthreads();

    if (tid < kV) {
        int any = 0;
        for (int d = 0; d < kD; ++d) any |= (s_emb[tid * kD + d] != 0.0f) ? 1 : 0;
        s_maskv[tid] = any;
    }

    const int tokL = s_tok[kT - 1];

    // ---- proj table: column 'tid' (coalesced global reads), then permuted
    // store so the step loop reads s_projP[v*256 + tid] = proj[v][col(tid)].
    float a0 = b_f[tid], a1 = a0, a2 = a0, a3 = a0, a4 = a0, a5 = a0;
    float accb = b_b[tid];
    for (int d = 0; d < kD; ++d) {
        const float wkf = Wk_f[d * kG + tid];
        const float wkb = Wk_b[d * kG + tid];
        a0 = fmaf(s_emb[0 * kD + d], wkf, a0);
        a1 = fmaf(s_emb[1 * kD + d], wkf, a1);
        a2 = fmaf(s_emb[2 * kD + d], wkf, a2);
        a3 = fmaf(s_emb[3 * kD + d], wkf, a3);
        a4 = fmaf(s_emb[4 * kD + d], wkf, a4);
        a5 = fmaf(s_emb[5 * kD + d], wkf, a5);
        accb = fmaf(s_emb[tokL * kD + d], wkb, accb);
    }
    {   // inverse permutation: lane q with col(q)==tid is q = w0*64 + k0*4 + g0
        const int g0 = tid >> 6, u0 = tid & 63, w0 = u0 >> 4, k0 = u0 & 15;
        const int q = w0 * 64 + k0 * 4 + g0;
        s_projP[0 * kG + q] = a0;
        s_projP[1 * kG + q] = a1;
        s_projP[2 * kG + q] = a2;
        s_projP[3 * kG + q] = a3;
        s_projP[4 * kG + q] = a4;
        s_projP[5 * kG + q] = a5;
    }

    // ---- backward single step: z = xproj_b only (h0=0, c0=0 -> f dead) ----
    float ab;
    if (tid < 128)      ab = sigmoid_f(accb);
    else if (tid < 192) ab = tanh_fast(accb);
    else                ab = sigmoid_f(accb);
    s_act[tid] = ab;
    __syncthreads();   // also makes s_maskv visible
    if (tid < kU) {
        const float cb = s_act[tid] * s_act[2 * kU + tid];
        const float hb = s_act[3 * kU + tid] * tanh_fast(cb);
        s_hb[tid] = s_maskv[tokL] ? hb : 0.0f;
    }

    // ---- recurrent weights: 16 NAMED float4 registers (no alloca!) ----
#define LDW(i)                                      \
    float4 w##i;                                    \
    w##i.x = Wr_f[(4 * i + 0) * kG + col];          \
    w##i.y = Wr_f[(4 * i + 1) * kG + col];          \
    w##i.z = Wr_f[(4 * i + 2) * kG + col];          \
    w##i.w = Wr_f[(4 * i + 3) * kG + col];
    LDW(0) LDW(1) LDW(2)  LDW(3)  LDW(4)  LDW(5)  LDW(6)  LDW(7)
    LDW(8) LDW(9) LDW(10) LDW(11) LDW(12) LDW(13) LDW(14) LDW(15)
#undef LDW

    float c = 0.0f, hreg = 0.0f;
    __syncthreads();   // projP + s_h init + s_hb visible

    // ---- software-pipelined token path ----
    int   tok  = s_tok[0];
    float zcur = s_projP[tok * kG + tid];
    int   msk  = s_maskv[tok];

    const int base = l & ~3;

    for (int t = 0; t < kT; ++t) {
        const int rp = t & 1, wp = rp ^ 1;

        // prefetch next step's token/proj/mask (projP is constant -> legal)
        const int   tokn  = s_tok[(t + 1) & (kT - 1)];
        const float znext = s_projP[tokn * kG + tid];
        const int   mskn  = s_maskv[tokn];

        const float4* hp = (const float4*)s_h[rp];

        // 64 MACs, 4 independent chains, fully named registers
        float z0 = zcur, z1 = 0.0f, z2 = 0.0f, z3 = 0.0f;
#define MAC(i)                                 \
        {                                      \
            const float4 h_ = hp[i];           \
            z0 = fmaf(h_.x, w##i.x, z0);       \
            z1 = fmaf(h_.y, w##i.y, z1);       \
            z2 = fmaf(h_.z, w##i.z, z2);       \
            z3 = fmaf(h_.w, w##i.w, z3);       \
        }
        MAC(0) MAC(1) MAC(2)  MAC(3)  MAC(4)  MAC(5)  MAC(6)  MAC(7)
        MAC(8) MAC(9) MAC(10) MAC(11) MAC(12) MAC(13) MAC(14) MAC(15)
#undef MAC
        const float z = (z0 + z1) + (z2 + z3);

        // one exp: gate 2 uses tanh(z) = 2*sigmoid(2z)-1
        const bool  isg = (g == 2);
        const float zz  = isg ? 2.0f * z : z;
        const float s   = 1.0f / (1.0f + __expf(-zz));
        const float a   = isg ? 2.0f * s - 1.0f : s;

        // gather i,f,g,o from the 4 lanes of this unit's quad
        const float ai = __shfl(a, base + 0, 64);
        const float af = __shfl(a, base + 1, 64);
        const float ag = __shfl(a, base + 2, 64);
        const float ao = __shfl(a, base + 3, 64);

        const float cn = fmaf(af, c, ai * ag);
        const float hn = ao * tanh_fast(cn);
        if (msk) { c = cn; hreg = hn; }

        if (g == 0) s_h[wp][u] = hreg;
        __syncthreads();

        zcur = znext; msk = mskn; tok = tokn;
    }

    // final h is in s_h[0] (step 1023 writes buffer (1024)&1 == 0)
    if (tid < kU) {
        float v = s_h[0][tid] * Wd[tid] + s_hb[tid] * Wd[kU + tid];
#pragma unroll
        for (int off = 32; off > 0; off >>= 1) v += __shfl_down(v, off, 64);
        if (tid == 0) out[b] = v + bd[0];
    }
}

extern "C" void kernel_launch(void* const* d_in, const int* in_sizes, int n_in,
                              void* d_out, int out_size, void* d_ws, size_t ws_size,
                              hipStream_t stream) {
    const int*   tokens = (const int*)d_in[0];
    const float* emb    = (const float*)d_in[1];
    const float* Wk_f   = (const float*)d_in[2];
    const float* Wr_f   = (const float*)d_in[3];
    const float* b_f    = (const float*)d_in[4];
    const float* Wk_b   = (const float*)d_in[5];
    // d_in[6] = Wr_b: unused (backward runs one step from h0=0)
    const float* b_b    = (const float*)d_in[7];
    const float* Wd     = (const float*)d_in[8];
    const float* bd     = (const float*)d_in[9];
    float* out = (float*)d_out;

    bilstm_last_kernel<<<kB, 256, 0, stream>>>(
        tokens, emb, Wk_f, Wr_f, b_f, Wk_b, b_b, Wd, bd, out);
}

// Round 5
// 429.433 us; speedup vs baseline: 1.6182x; 1.6057x over previous
//
#include <hip/hip_runtime.h>

// Bidirectional LSTM, B=256, T=1024, V=6, D=64, U=64; out = last-step
// concat(h_f, h_b) @ Wd + bd, shape (B,1).
// Reductions: backward dir = ONE step from h0=0 (Wr_b dead); V=6 -> xproj is
// a 6x256 table per block; mask is a 6-bit register (ballot over emb rows).
// R5 structure (per batch = 1 block = 4 waves):
//   lane 4k+s of wave w owns unit u=16w+k, h-slice s (16 floats):
//   - 4x ds_read_b128 per lane (was 16) -> 4x less LDS-pipe pressure
//   - partial dots for ALL 4 gates over slice s, then 2-round quad butterfly
//     via DPP quad_perm (VALU, replaces 4 ds_bpermute shuffles) -> every lane
//     holds all 4 gate z's; c,h updated redundantly in-quad (no gather).
//   - sigmoid/tanh via v_rcp_f32 (1 ulp; threshold slack ~1e5x)
//   - token prefetch depth 2: no dependent LDS-LDS chain inside a step
//   - ONE __syncthreads per step (double-buffered h)

constexpr int kB = 256;
constexpr int kT = 1024;
constexpr int kV = 6;
constexpr int kD = 64;
constexpr int kU = 64;
constexpr int kG = 256; // 4*U gate columns

__device__ __forceinline__ float fast_rcp(float x) { return __builtin_amdgcn_rcpf(x); }
__device__ __forceinline__ float sig_f(float z)  { return fast_rcp(1.0f + __expf(-z)); }
__device__ __forceinline__ float tanh_f(float z) { return 2.0f * fast_rcp(1.0f + __expf(-2.0f * z)) - 1.0f; }

// quad_perm DPP xor-add: lane i += lane (i^1) / (i^2) within each quad
template <int CTRL>
__device__ __forceinline__ float dpp_addq(float x) {
    const int y = __builtin_amdgcn_mov_dpp(__float_as_int(x), CTRL, 0xF, 0xF, true);
    return x + __int_as_float(y);
}
constexpr int kXor1 = 0xB1; // quad_perm(1,0,3,2)
constexpr int kXor2 = 0x4E; // quad_perm(2,3,0,1)

__global__ __launch_bounds__(256, 1) void bilstm_last_kernel(
    const int*   __restrict__ tokens, // (B,T)
    const float* __restrict__ emb,    // (6,64)
    const float* __restrict__ Wk_f,   // (64,256)
    const float* __restrict__ Wr_f,   // (64,256)
    const float* __restrict__ b_f,    // (256)
    const float* __restrict__ Wk_b,   // (64,256)
    const float* __restrict__ b_b,    // (256)
    const float* __restrict__ Wd,     // (128)
    const float* __restrict__ bd,     // (1)
    float*       __restrict__ out)    // (B)
{
    __shared__ float s_emb[kV * kD];
    __shared__ float s_projP[kV * kG];            // PERMUTED xproj_f table
    __shared__ int   s_tok[kT];
    __shared__ float __align__(16) s_h[2][kU];    // double-buffered hidden
    __shared__ float s_act[kG];                   // backward-step scratch

    const int b   = blockIdx.x;
    const int tid = threadIdx.x;
    const int l   = tid & 63;       // lane in wave
    const int wv  = tid >> 6;       // wave id 0..3
    const int s   = l & 3;          // h-slice 0..3 (16 floats each)
    const int k   = l >> 2;         // 0..15
    const int u   = wv * 16 + k;    // unit owned by this quad

    // ---- stage emb + tokens ----
    for (int i = tid; i < kV * kD; i += 256) s_emb[i] = emb[i];
    ((int4*)s_tok)[tid] = ((const int4*)(tokens + b * kT))[tid];
    if (tid < kU) { s_h[0][tid] = 0.0f; s_h[1][tid] = 0.0f; }
    __syncthreads();

    // ---- 6-bit mask register: bit v = any(emb[v][:] != 0) (wave ballot) ----
    unsigned int mb = 0;
#pragma unroll
    for (int v = 0; v < kV; ++v) {
        const unsigned long long bb = __ballot(s_emb[v * kD + l] != 0.0f);
        mb |= (bb != 0ull) ? (1u << v) : 0u;
    }

    const int tokL = s_tok[kT - 1];

    // ---- proj table: column 'tid' (coalesced), stored PERMUTED so the step
    // loop's lane q reads s_projP[v*256+q] = proj[v][ (q&3)*64 + u(q) ]
    // (i.e. gate index = slice index s -- the butterfly seeds gate s there).
    float a0 = b_f[tid], a1 = a0, a2 = a0, a3 = a0, a4 = a0, a5 = a0;
    float accb = b_b[tid];
    for (int d = 0; d < kD; ++d) {
        const float wkf = Wk_f[d * kG + tid];
        const float wkb = Wk_b[d * kG + tid];
        a0 = fmaf(s_emb[0 * kD + d], wkf, a0);
        a1 = fmaf(s_emb[1 * kD + d], wkf, a1);
        a2 = fmaf(s_emb[2 * kD + d], wkf, a2);
        a3 = fmaf(s_emb[3 * kD + d], wkf, a3);
        a4 = fmaf(s_emb[4 * kD + d], wkf, a4);
        a5 = fmaf(s_emb[5 * kD + d], wkf, a5);
        accb = fmaf(s_emb[tokL * kD + d], wkb, accb);
    }
    {   // inverse perm: lane q wanting column 'tid' is q = w0*64 + k0*4 + g0
        const int g0 = tid >> 6, u0 = tid & 63, w0 = u0 >> 4, k0 = u0 & 15;
        const int q = w0 * 64 + k0 * 4 + g0;
        s_projP[0 * kG + q] = a0;
        s_projP[1 * kG + q] = a1;
        s_projP[2 * kG + q] = a2;
        s_projP[3 * kG + q] = a3;
        s_projP[4 * kG + q] = a4;
        s_projP[5 * kG + q] = a5;
    }

    // ---- backward single step: z = xproj_b only (h0=0, c0=0 -> f dead) ----
    float ab;
    if (tid < 128)      ab = sig_f(accb);
    else if (tid < 192) ab = tanh_f(accb);
    else                ab = sig_f(accb);
    s_act[tid] = ab;
    __syncthreads();
    float hb_val = 0.0f;
    if (tid < kU) {
        const float cb = s_act[tid] * s_act[2 * kU + tid];
        const float hb = s_act[3 * kU + tid] * tanh_f(cb);
        hb_val = ((mb >> tokL) & 1) ? hb : 0.0f;   // kept in register (tid<64)
    }

    // ---- recurrent weights: 16 named float4 = rows 16s+4jb+{0..3}, col g*64+u
#define DECLW(g, jb)                                                  \
    float4 wq##g##_##jb;                                              \
    wq##g##_##jb.x = Wr_f[(16 * s + 4 * jb + 0) * kG + (g * 64 + u)]; \
    wq##g##_##jb.y = Wr_f[(16 * s + 4 * jb + 1) * kG + (g * 64 + u)]; \
    wq##g##_##jb.z = Wr_f[(16 * s + 4 * jb + 2) * kG + (g * 64 + u)]; \
    wq##g##_##jb.w = Wr_f[(16 * s + 4 * jb + 3) * kG + (g * 64 + u)];
    DECLW(0,0) DECLW(0,1) DECLW(0,2) DECLW(0,3)
    DECLW(1,0) DECLW(1,1) DECLW(1,2) DECLW(1,3)
    DECLW(2,0) DECLW(2,1) DECLW(2,2) DECLW(2,3)
    DECLW(3,0) DECLW(3,1) DECLW(3,2) DECLW(3,3)
#undef DECLW

    float c = 0.0f, hreg = 0.0f;
    __syncthreads();   // projP + s_h init visible

    // ---- token pipeline, depth 2 ----
    const int tok0 = s_tok[0];
    float zcur = s_projP[tok0 * kG + tid];   // gate-s proj for this lane
    int   msk  = (mb >> tok0) & 1;
    int   tokA = s_tok[1];                   // token[t+1]

    for (int t = 0; t < kT; ++t) {
        const int rp = t & 1, wp = rp ^ 1;

        // prefetches: all off the critical path, no LDS->LDS dependence
        const float znext = s_projP[tokA * kG + tid];
        const int   mskn  = (mb >> tokA) & 1;
        const int   tokB  = s_tok[(t + 2) & (kT - 1)];

        // h slice s: 4x ds_read_b128 (2-way bank aliasing = free)
        const float4* hp = (const float4*)s_h[rp];
        const float4 hv0 = hp[s * 4 + 0];
        const float4 hv1 = hp[s * 4 + 1];
        const float4 hv2 = hp[s * 4 + 2];
        const float4 hv3 = hp[s * 4 + 3];

        // 4 gate-partials over this slice; gate s seeded with proj+bias
        float p0 = (s == 0) ? zcur : 0.0f;
        float p1 = (s == 1) ? zcur : 0.0f;
        float p2 = (s == 2) ? zcur : 0.0f;
        float p3 = (s == 3) ? zcur : 0.0f;
#define MACQ(g, jb)                                  \
        p##g = fmaf(hv##jb.x, wq##g##_##jb.x, p##g); \
        p##g = fmaf(hv##jb.y, wq##g##_##jb.y, p##g); \
        p##g = fmaf(hv##jb.z, wq##g##_##jb.z, p##g); \
        p##g = fmaf(hv##jb.w, wq##g##_##jb.w, p##g);
        MACQ(0,0) MACQ(1,0) MACQ(2,0) MACQ(3,0)
        MACQ(0,1) MACQ(1,1) MACQ(2,1) MACQ(3,1)
        MACQ(0,2) MACQ(1,2) MACQ(2,2) MACQ(3,2)
        MACQ(0,3) MACQ(1,3) MACQ(2,3) MACQ(3,3)
#undef MACQ

        // quad butterfly (DPP): every lane gets all 4 complete gate sums
        p0 = dpp_addq<kXor1>(p0); p1 = dpp_addq<kXor1>(p1);
        p2 = dpp_addq<kXor1>(p2); p3 = dpp_addq<kXor1>(p3);
        p0 = dpp_addq<kXor2>(p0); p1 = dpp_addq<kXor2>(p1);
        p2 = dpp_addq<kXor2>(p2); p3 = dpp_addq<kXor2>(p3);

        // activations (all lanes, redundant per quad)
        const float ai = sig_f(p0);
        const float af = sig_f(p1);
        const float ag = tanh_f(p2);
        const float ao = sig_f(p3);
        const float cn = fmaf(af, c, ai * ag);
        const float hn = ao * tanh_f(cn);
        if (msk) { c = cn; hreg = hn; }

        if (s == 0) s_h[wp][u] = hreg;
        __syncthreads();

        zcur = znext; msk = mskn; tokA = tokB;
    }

    // ---- epilogue: out[b] = h_f . Wd[0:64] + h_b . Wd[64:128] + bd ----
    if (tid < kU) {
        float v = s_h[0][tid] * Wd[tid] + hb_val * Wd[kU + tid];
#pragma unroll
        for (int off = 32; off > 0; off >>= 1) v += __shfl_down(v, off, 64);
        if (tid == 0) out[b] = v + bd[0];
    }
}

extern "C" void kernel_launch(void* const* d_in, const int* in_sizes, int n_in,
                              void* d_out, int out_size, void* d_ws, size_t ws_size,
                              hipStream_t stream) {
    const int*   tokens = (const int*)d_in[0];
    const float* emb    = (const float*)d_in[1];
    const float* Wk_f   = (const float*)d_in[2];
    const float* Wr_f   = (const float*)d_in[3];
    const float* b_f    = (const float*)d_in[4];
    const float* Wk_b   = (const float*)d_in[5];
    // d_in[6] = Wr_b: unused (backward runs one step from h0=0)
    const float* b_b    = (const float*)d_in[7];
    const float* Wd     = (const float*)d_in[8];
    const float* bd     = (const float*)d_in[9];
    float* out = (float*)d_out;

    bilstm_last_kernel<<<kB, 256, 0, stream>>>(
        tokens, emb, Wk_f, Wr_f, b_f, Wk_b, b_b, Wd, bd, out);
}

// Round 6
// 391.578 us; speedup vs baseline: 1.7746x; 1.0967x over previous
//
#include <hip/hip_runtime.h>

// Bidirectional LSTM, B=256, T=1024, V=6, D=64, U=64; out = last-step
// concat(h_f, h_b) @ Wd + bd, shape (B,1).
// Reductions: backward dir = ONE step from h0=0 (Wr_b dead); V=6 -> xproj is
// a 6x256 table; mask = 6-bit scalar (ballot over emb rows).
// R5: quad-sliced dots + DPP butterfly, 1 barrier/step (386us, VALUBusy 56%).
// R6: cut VALU -- (a) transpose-butterfly so each lane activates ONLY its own
//     gate (4 transcendentals/step, was 10), then 4 DPP quad-broadcasts;
//     (b) scalar token pipeline via readfirstlane (mask = SGPR bit, proj addr
//     = s_lshl+v_add); (c) no seed selects (proj added after reduction);
//     (d) hand-unrolled x2 for static buffer parity.

constexpr int kB = 256;
constexpr int kT = 1024;
constexpr int kV = 6;
constexpr int kD = 64;
constexpr int kU = 64;
constexpr int kG = 256; // 4*U gate columns

#define LOG2E 1.44269504f

template <int CTRL>
__device__ __forceinline__ float dppf(float x) {
    return __int_as_float(
        __builtin_amdgcn_mov_dpp(__float_as_int(x), CTRL, 0xF, 0xF, true));
}
constexpr int kXor1 = 0xB1; // quad_perm(1,0,3,2)
constexpr int kXor2 = 0x4E; // quad_perm(2,3,0,1)
constexpr int kB0 = 0x00, kB1 = 0x55, kB2 = 0xAA, kB3 = 0xFF; // quad bcasts

__device__ __forceinline__ float fast_rcp(float x) { return __builtin_amdgcn_rcpf(x); }
__device__ __forceinline__ float exp2_f(float x)   { return __builtin_amdgcn_exp2f(x); }
__device__ __forceinline__ float sig_f(float z)  { return fast_rcp(1.0f + exp2_f(-LOG2E * z)); }
__device__ __forceinline__ float tanh_f(float z) { return 2.0f * fast_rcp(1.0f + exp2_f(-2.0f * LOG2E * z)) - 1.0f; }

__global__ __launch_bounds__(256, 1) void bilstm_last_kernel(
    const int*   __restrict__ tokens, // (B,T)
    const float* __restrict__ emb,    // (6,64)
    const float* __restrict__ Wk_f,   // (64,256)
    const float* __restrict__ Wr_f,   // (64,256)
    const float* __restrict__ b_f,    // (256)
    const float* __restrict__ Wk_b,   // (64,256)
    const float* __restrict__ b_b,    // (256)
    const float* __restrict__ Wd,     // (128)
    const float* __restrict__ bd,     // (1)
    float*       __restrict__ out)    // (B)
{
    __shared__ float s_emb[kV * kD];
    __shared__ float s_projP[kV * kG];            // PERMUTED xproj_f table
    __shared__ int   s_tok[kT];
    __shared__ float __align__(16) s_h[2][kU];    // double-buffered hidden
    __shared__ float s_act[kG];                   // backward-step scratch

    const int b   = blockIdx.x;
    const int tid = threadIdx.x;
    const int l   = tid & 63;       // lane in wave
    const int wv  = tid >> 6;       // wave id 0..3
    const int s   = l & 3;          // h-slice AND owned gate (0..3 = i,f,g,o)
    const int k   = l >> 2;         // 0..15
    const int u   = wv * 16 + k;    // unit owned by this quad

    // ---- stage emb + tokens ----
    for (int i = tid; i < kV * kD; i += 256) s_emb[i] = emb[i];
    ((int4*)s_tok)[tid] = ((const int4*)(tokens + b * kT))[tid];
    if (tid < kU) { s_h[0][tid] = 0.0f; s_h[1][tid] = 0.0f; }
    __syncthreads();

    // ---- 6-bit mask, scalarized: bit v = any(emb[v][:] != 0) ----
    unsigned int mbv = 0;
#pragma unroll
    for (int v = 0; v < kV; ++v) {
        const unsigned long long bb = __ballot(s_emb[v * kD + l] != 0.0f);
        mbv |= (bb != 0ull) ? (1u << v) : 0u;
    }
    const unsigned int smb = __builtin_amdgcn_readfirstlane(mbv);

    const int tokL = s_tok[kT - 1];

    // ---- proj table (coalesced global reads), stored PERMUTED so lane q of
    // the step loop reads proj[v][ (q&3)*64 + u(q) ] at s_projP[v*256+q].
    float a0 = b_f[tid], a1 = a0, a2 = a0, a3 = a0, a4 = a0, a5 = a0;
    float accb = b_b[tid];
    for (int d = 0; d < kD; ++d) {
        const float wkf = Wk_f[d * kG + tid];
        const float wkb = Wk_b[d * kG + tid];
        a0 = fmaf(s_emb[0 * kD + d], wkf, a0);
        a1 = fmaf(s_emb[1 * kD + d], wkf, a1);
        a2 = fmaf(s_emb[2 * kD + d], wkf, a2);
        a3 = fmaf(s_emb[3 * kD + d], wkf, a3);
        a4 = fmaf(s_emb[4 * kD + d], wkf, a4);
        a5 = fmaf(s_emb[5 * kD + d], wkf, a5);
        accb = fmaf(s_emb[tokL * kD + d], wkb, accb);
    }
    {   // inverse perm: lane q wanting column 'tid' is q = w0*64 + k0*4 + g0
        const int g0 = tid >> 6, u0 = tid & 63, w0 = u0 >> 4, k0 = u0 & 15;
        const int q = w0 * 64 + k0 * 4 + g0;
        s_projP[0 * kG + q] = a0;
        s_projP[1 * kG + q] = a1;
        s_projP[2 * kG + q] = a2;
        s_projP[3 * kG + q] = a3;
        s_projP[4 * kG + q] = a4;
        s_projP[5 * kG + q] = a5;
    }

    // ---- backward single step: z = xproj_b only (h0=0, c0=0 -> f dead) ----
    float ab;
    if (tid < 128)      ab = sig_f(accb);
    else if (tid < 192) ab = tanh_f(accb);
    else                ab = sig_f(accb);
    s_act[tid] = ab;
    __syncthreads();
    float hb_val = 0.0f;
    if (tid < kU) {
        const float cb = s_act[tid] * s_act[2 * kU + tid];
        const float hb = s_act[3 * kU + tid] * tanh_f(cb);
        hb_val = ((smb >> tokL) & 1) ? hb : 0.0f;
    }

    // ---- recurrent weights: 16 named float4 (unified VGPR/AGPR file) ----
#define DECLW(g, jb)                                                  \
    float4 wq##g##_##jb;                                              \
    wq##g##_##jb.x = Wr_f[(16 * s + 4 * jb + 0) * kG + (g * 64 + u)]; \
    wq##g##_##jb.y = Wr_f[(16 * s + 4 * jb + 1) * kG + (g * 64 + u)]; \
    wq##g##_##jb.z = Wr_f[(16 * s + 4 * jb + 2) * kG + (g * 64 + u)]; \
    wq##g##_##jb.w = Wr_f[(16 * s + 4 * jb + 3) * kG + (g * 64 + u)];
    DECLW(0,0) DECLW(0,1) DECLW(0,2) DECLW(0,3)
    DECLW(1,0) DECLW(1,1) DECLW(1,2) DECLW(1,3)
    DECLW(2,0) DECLW(2,1) DECLW(2,2) DECLW(2,3)
    DECLW(3,0) DECLW(3,1) DECLW(3,2) DECLW(3,3)
#undef DECLW

    // per-lane activation constants: gate s==2 is tanh, others sigmoid
    const bool  isg    = (s == 2);
    const float aScale = isg ? -2.0f * LOG2E : -LOG2E; // exp2(z*aScale)=exp(-zz)
    const float aMul   = isg ? 2.0f : 1.0f;
    const float aAdd   = isg ? -1.0f : 0.0f;

    float c = 0.0f, hreg = 0.0f;
    __syncthreads();   // projP + s_h init visible

    // ---- scalar token pipeline, depth 2 ----
    int stok0 = __builtin_amdgcn_readfirstlane(s_tok[0]);
    float zcur = s_projP[stok0 * kG + tid];   // own-gate proj for this lane
    int   mskc = (smb >> stok0) & 1;          // scalar
    int   stokA = __builtin_amdgcn_readfirstlane(s_tok[1]);

#define STEP(RP, WP, TT)                                                      \
    {                                                                         \
        const int   vtokB = s_tok[((TT) + 2) & (kT - 1)];                     \
        const float znext = s_projP[stokA * kG + tid];                        \
        const int   mskn  = (int)((smb >> stokA) & 1);                        \
        const float4* hp = (const float4*)s_h[RP];                            \
        const float4 hv0 = hp[s * 4 + 0];                                     \
        const float4 hv1 = hp[s * 4 + 1];                                     \
        const float4 hv2 = hp[s * 4 + 2];                                     \
        const float4 hv3 = hp[s * 4 + 3];                                     \
        float p0 = 0.0f, p1 = 0.0f, p2 = 0.0f, p3 = 0.0f;                     \
        MACQ(0,0) MACQ(1,0) MACQ(2,0) MACQ(3,0)                               \
        MACQ(0,1) MACQ(1,1) MACQ(2,1) MACQ(3,1)                               \
        MACQ(0,2) MACQ(1,2) MACQ(2,2) MACQ(3,2)                               \
        MACQ(0,3) MACQ(1,3) MACQ(2,3) MACQ(3,3)                               \
        /* round 1: 2-lane sums over xor1 pairs, all gates */                 \
        p0 += dppf<kXor1>(p0); p1 += dppf<kXor1>(p1);                         \
        p2 += dppf<kXor1>(p2); p3 += dppf<kXor1>(p3);                         \
        /* select own pair-gate (xor2 partner has same s&1 -> gate-uniform) */\
        float X = (s & 1) ? p1 : p0;                                          \
        float Y = (s & 1) ? p3 : p2;                                          \
        X += dppf<kXor2>(X); Y += dppf<kXor2>(Y);                             \
        const float z = ((s & 2) ? Y : X) + zcur;                             \
        /* one activation per lane (own gate) */                              \
        const float e = exp2_f(z * aScale);                                   \
        const float r = fast_rcp(1.0f + e);                                   \
        const float a = fmaf(r, aMul, aAdd);                                  \
        /* quad broadcasts: gate q lives in lane q of the quad */             \
        const float ai = dppf<kB0>(a);                                        \
        const float af = dppf<kB1>(a);                                        \
        const float ag = dppf<kB2>(a);                                        \
        const float ao = dppf<kB3>(a);                                        \
        const float cn = fmaf(af, c, ai * ag);                                \
        const float hn = ao * tanh_f(cn);                                     \
        if (mskc) { c = cn; hreg = hn; }   /* uniform branch */               \
        if (s == 0) s_h[WP][u] = hreg;                                        \
        __syncthreads();                                                      \
        zcur = znext; mskc = mskn; stokA = __builtin_amdgcn_readfirstlane(vtokB); \
    }

#define MACQ(g, jb)                                  \
        p##g = fmaf(hv##jb.x, wq##g##_##jb.x, p##g); \
        p##g = fmaf(hv##jb.y, wq##g##_##jb.y, p##g); \
        p##g = fmaf(hv##jb.z, wq##g##_##jb.z, p##g); \
        p##g = fmaf(hv##jb.w, wq##g##_##jb.w, p##g);

    for (int t = 0; t < kT; t += 2) {
        STEP(0, 1, t)
        STEP(1, 0, t + 1)
    }
#undef MACQ
#undef STEP

    // final h in s_h[0] (step 1023 reads s_h[1], writes s_h[0])
    if (tid < kU) {
        float v = s_h[0][tid] * Wd[tid] + hb_val * Wd[kU + tid];
#pragma unroll
        for (int off = 32; off > 0; off >>= 1) v += __shfl_down(v, off, 64);
        if (tid == 0) out[b] = v + bd[0];
    }
}

extern "C" void kernel_launch(void* const* d_in, const int* in_sizes, int n_in,
                              void* d_out, int out_size, void* d_ws, size_t ws_size,
                              hipStream_t stream) {
    const int*   tokens = (const int*)d_in[0];
    const float* emb    = (const float*)d_in[1];
    const float* Wk_f   = (const float*)d_in[2];
    const float* Wr_f   = (const float*)d_in[3];
    const float* b_f    = (const float*)d_in[4];
    const float* Wk_b   = (const float*)d_in[5];
    // d_in[6] = Wr_b: unused (backward runs one step from h0=0)
    const float* b_b    = (const float*)d_in[7];
    const float* Wd     = (const float*)d_in[8];
    const float* bd     = (const float*)d_in[9];
    float* out = (float*)d_out;

    bilstm_last_kernel<<<kB, 256, 0, stream>>>(
        tokens, emb, Wk_f, Wr_f, b_f, Wk_b, b_b, Wd, bd, out);
}